// Round 9
// baseline (34.771 us; speedup 1.0000x reference)
//
#include <hip/hip_runtime.h>

// Ray-sphere intersection: N rays x 64 moving spheres -> closest hit distance.
// x: (1, N, 7) f32 = [origin(3), t_ray(1), direction(3)]
// z: (1, 384) f32 = 64 spheres x [center(3), velocity(3)]
// out: mu (N) ++ sigma (N), f32
//
// R9 structure: pack along the SPHERE axis. z is staged once per block into
// LDS transposed (zp[c][s]) so each sphere-PAIR component is a ds_read_b64
// directly into a VGPR pair -> every mixing op is a true v_pk_* op. Ray
// values are hoisted splat pairs (built once). Previously sphere scalars
// were broadcast per-op, which scalarized 6 pk ops/sphere (~40% extra VALU).
//
// FROZEN ARITHMETIC (R3/R5/R8-proven, elementwise identical here):
//   oc = fma(v, t, c - o); b = fma(dx,ocx,fma(dy,ocy,dz*ocz));
//   csq = fma(ocx,ocx,fma(ocy,ocy,ocz*ocz)); disc = fma(b,b, 1 - csq);
//   sq = raw v_sqrt(disc) (disc<0 -> NaN -> compares false -> BIG);
//   r = t0>0 ? t0 : (t1>0 ? t1 : BIG);  closest = fmin(closest, r).
// Unsigned-bit-min tail is BANNED (failed R4, R7). Min over spheres is
// order-invariant (candidates are reals or BIG, never NaN).

typedef float v2f __attribute__((ext_vector_type(2)));

constexpr float BIGF = 1e10f;

__global__ __launch_bounds__(256, 4) void ray_sphere_kernel(
    const float* __restrict__ x, const float* __restrict__ z,
    float* __restrict__ out, int N)
{
    __shared__ float zp[6][64];   // zp[c][s] = component c of sphere s

    int tidb = threadIdx.x;
    int tid  = blockIdx.x * 256 + tidb;
    long n0  = (long)tid * 2;     // 2 rays per thread (grid exactly covers N)

    // Issue ray loads first: 14 floats, 8B-aligned -> 7x global_load_dwordx2
    const float2* xr = (const float2*)(x + n0 * 7);
    float2 w0 = xr[0], w1 = xr[1], w2 = xr[2], w3 = xr[3],
           w4 = xr[4], w5 = xr[5], w6 = xr[6];

    // Stage z transposed into LDS (384 elements, 256 threads: i and i+256)
    {
        int i = tidb;
        int s = i / 6, c = i - s * 6;
        zp[c][s] = z[i];
        if (tidb < 128) {
            int i2 = tidb + 256;
            int s2 = i2 / 6, c2 = i2 - s2 * 6;
            zp[c2][s2] = z[i2];
        }
    }
    __syncthreads();

    // Unpack rays (mapping R8-proven)
    float ox0 = w0.x, oy0 = w0.y, oz0 = w1.x, tr0 = w1.y,
          dx0 = w2.x, dy0 = w2.y, dz0 = w3.x;
    float ox1 = w3.y, oy1 = w4.x, oz1 = w4.y, tr1 = w5.x,
          dx1 = w5.y, dy1 = w6.x, dz1 = w6.y;

    // normalize d: d / (sqrt(|d|^2) + 1e-12)   (FROZEN, scalar per ray)
    {
        float n2 = fmaf(dx0, dx0, fmaf(dy0, dy0, dz0 * dz0));
        float inv = __builtin_amdgcn_rcpf(__builtin_amdgcn_sqrtf(n2) + 1e-12f);
        dx0 *= inv; dy0 *= inv; dz0 *= inv;
    }
    {
        float n2 = fmaf(dx1, dx1, fmaf(dy1, dy1, dz1 * dz1));
        float inv = __builtin_amdgcn_rcpf(__builtin_amdgcn_sqrtf(n2) + 1e-12f);
        dx1 *= inv; dy1 *= inv; dz1 *= inv;
    }

    // Hoisted splat pairs (built once, loop-invariant)
    v2f oxA = {ox0, ox0}, oyA = {oy0, oy0}, ozA = {oz0, oz0}, tA = {tr0, tr0};
    v2f dxA = {dx0, dx0}, dyA = {dy0, dy0}, dzA = {dz0, dz0};
    v2f oxB = {ox1, ox1}, oyB = {oy1, oy1}, ozB = {oz1, oz1}, tB = {tr1, tr1};
    v2f dxB = {dx1, dx1}, dyB = {dy1, dy1}, dzB = {dz1, dz1};

    float clA = BIGF, clB = BIGF;

    #pragma unroll 8
    for (int j = 0; j < 32; ++j) {     // sphere pair {2j, 2j+1}
        v2f cx = *(const v2f*)&zp[0][2 * j];   // ds_read_b64, broadcast
        v2f cy = *(const v2f*)&zp[1][2 * j];
        v2f cz = *(const v2f*)&zp[2][2 * j];
        v2f vx = *(const v2f*)&zp[3][2 * j];
        v2f vy = *(const v2f*)&zp[4][2 * j];
        v2f vz = *(const v2f*)&zp[5][2 * j];

        // ---- ray A ----
        {
            v2f ocx = __builtin_elementwise_fma(vx, tA, cx - oxA);
            v2f ocy = __builtin_elementwise_fma(vy, tA, cy - oyA);
            v2f ocz = __builtin_elementwise_fma(vz, tA, cz - ozA);
            v2f b   = __builtin_elementwise_fma(dxA, ocx,
                      __builtin_elementwise_fma(dyA, ocy, dzA * ocz));
            v2f csq = __builtin_elementwise_fma(ocx, ocx,
                      __builtin_elementwise_fma(ocy, ocy, ocz * ocz));
            v2f disc = __builtin_elementwise_fma(b, b, (v2f){1.0f, 1.0f} - csq);
            v2f sq;
            sq[0] = __builtin_amdgcn_sqrtf(disc[0]);
            sq[1] = __builtin_amdgcn_sqrtf(disc[1]);
            v2f t0 = b - sq;
            v2f t1 = b + sq;
            #pragma unroll
            for (int k = 0; k < 2; ++k) {
                float r1 = (t1[k] > 0.0f) ? t1[k] : BIGF;
                float r  = (t0[k] > 0.0f) ? t0[k] : r1;
                clA = fminf(clA, r);
            }
        }
        // ---- ray B ----
        {
            v2f ocx = __builtin_elementwise_fma(vx, tB, cx - oxB);
            v2f ocy = __builtin_elementwise_fma(vy, tB, cy - oyB);
            v2f ocz = __builtin_elementwise_fma(vz, tB, cz - ozB);
            v2f b   = __builtin_elementwise_fma(dxB, ocx,
                      __builtin_elementwise_fma(dyB, ocy, dzB * ocz));
            v2f csq = __builtin_elementwise_fma(ocx, ocx,
                      __builtin_elementwise_fma(ocy, ocy, ocz * ocz));
            v2f disc = __builtin_elementwise_fma(b, b, (v2f){1.0f, 1.0f} - csq);
            v2f sq;
            sq[0] = __builtin_amdgcn_sqrtf(disc[0]);
            sq[1] = __builtin_amdgcn_sqrtf(disc[1]);
            v2f t0 = b - sq;
            v2f t1 = b + sq;
            #pragma unroll
            for (int k = 0; k < 2; ++k) {
                float r1 = (t1[k] > 0.0f) ? t1[k] : BIGF;
                float r  = (t0[k] > 0.0f) ? t0[k] : r1;
                clB = fminf(clB, r);
            }
        }
    }

    *(float2*)(out + n0)     = make_float2(clA, clB);
    *(float2*)(out + N + n0) = make_float2(0.002f, 0.002f);
}

extern "C" void kernel_launch(void* const* d_in, const int* in_sizes, int n_in,
                              void* d_out, int out_size, void* d_ws, size_t ws_size,
                              hipStream_t stream) {
    const float* x = (const float*)d_in[0];
    const float* z = (const float*)d_in[1];
    float* out = (float*)d_out;
    int N = in_sizes[0] / 7;   // 1048576

    int threads = N / 2;
    int blocks = (threads + 255) / 256;   // 2048
    ray_sphere_kernel<<<blocks, 256, 0, stream>>>(x, z, out, N);
}